// Round 4
// baseline (232.230 us; speedup 1.0000x reference)
//
#include <hip/hip_runtime.h>

#define AS1 __attribute__((address_space(1)))
#define AS3 __attribute__((address_space(3)))

using f32x4 = __attribute__((ext_vector_type(4))) float;
using s16x8 = __attribute__((ext_vector_type(8))) short;
using u16x4 = __attribute__((ext_vector_type(4))) unsigned short;

__device__ __forceinline__ unsigned short f2bf(float f) {
  union { float f; unsigned u; } v; v.f = f;
  unsigned u = v.u;
  return (unsigned short)((u + 0x7FFFu + ((u >> 16) & 1u)) >> 16);  // RNE
}

__device__ __forceinline__ unsigned short f2bf_trunc(float f) {
  union { float f; unsigned u; } v; v.f = f;
  return (unsigned short)(v.u >> 16);  // truncate: fine for P in [0,1]
}

__device__ __forceinline__ void load_lds16(const void* g, void* l) {
  __builtin_amdgcn_global_load_lds((const AS1 void*)g, (AS3 void*)l, 16, 0, 0);
}

// ---------------- fp32 -> bf16 cast (x) ----------------
__global__ __launch_bounds__(256) void f32_to_bf16_kernel(const float* __restrict__ in,
                                                          unsigned short* __restrict__ out,
                                                          int n4) {
  int i = blockIdx.x * 256 + threadIdx.x;
  if (i < n4) {
    float4 v = ((const float4*)in)[i];
    u16x4 o;
    o.x = f2bf(v.x); o.y = f2bf(v.y); o.z = f2bf(v.z); o.w = f2bf(v.w);
    ((u16x4*)out)[i] = o;
  }
}

// ---------------- fp32 [R][C] -> bf16 [C][R] transpose (weights) ----------------
__global__ __launch_bounds__(256) void transpose_f32_bf16(const float* __restrict__ in,
                                                          unsigned short* __restrict__ out,
                                                          int R, int C) {
  __shared__ float tile[32][33];
  int x = blockIdx.x * 32 + threadIdx.x;
  int y0 = blockIdx.y * 32;
  for (int j = threadIdx.y; j < 32; j += 8)
    tile[j][threadIdx.x] = in[(size_t)(y0 + j) * C + x];
  __syncthreads();
  int x2 = blockIdx.y * 32 + threadIdx.x;
  int y2 = blockIdx.x * 32;
  for (int j = threadIdx.y; j < 32; j += 8)
    out[(size_t)(y2 + j) * R + x2] = f2bf(tile[threadIdx.x][j]);
}

// ---------------- V transpose: qkv V block [s][d] -> Vt[b][h][d][s] ----------------
__global__ __launch_bounds__(256) void transpose_v(const unsigned short* __restrict__ qkv,
                                                   unsigned short* __restrict__ Vt) {
  __shared__ unsigned short tile[64][65];
  const int tid = threadIdx.x;
  const int bh = blockIdx.y, b = bh >> 4, h = bh & 15;
  const int s0 = blockIdx.x * 64;
#pragma unroll
  for (int it = 0; it < 2; ++it) {
    int c = tid + it * 256;
    int row = c >> 3, cc = c & 7;
    s16x8 v = *(const s16x8*)(qkv + (size_t)(b * 2048 + s0 + row) * 3072 + 2048 + h * 64 + cc * 8);
#pragma unroll
    for (int j = 0; j < 8; ++j) tile[row][cc * 8 + j] = (unsigned short)v[j];
  }
  __syncthreads();
#pragma unroll
  for (int it = 0; it < 2; ++it) {
    int c = tid + it * 256;
    int d = c >> 3, sc = c & 7;
    s16x8 o;
#pragma unroll
    for (int j = 0; j < 8; ++j) o[j] = (short)tile[sc * 8 + j][d];
    *(s16x8*)(Vt + (size_t)bh * 64 * 2048 + (size_t)d * 2048 + s0 + sc * 8) = o;
  }
}

// ---------------- bf16 GEMM: C[M,N] = A[M,K] * Bt[N,K]^T (m97 structure) ----------------
template <bool OUT_BF16>
__global__ __launch_bounds__(256) void gemm_bt(const unsigned short* __restrict__ A,
                                               const unsigned short* __restrict__ Bt,
                                               void* __restrict__ Cout,
                                               int M, int N, int K) {
  __shared__ unsigned short As[128 * 32];
  __shared__ unsigned short Bs[128 * 32];
  const int tid = threadIdx.x;
  const int wave = tid >> 6, lane = tid & 63;
  const int l15 = lane & 15, quad = lane >> 4;
  const int wm = wave & 1, wn = wave >> 1;
  const int bm = blockIdx.y, bn = blockIdx.x;

  f32x4 acc[4][4] = {};

  const int c0 = wave * 128 + lane;
  for (int k0 = 0; k0 < K; k0 += 32) {
    __syncthreads();
#pragma unroll
    for (int s = 0; s < 2; ++s) {
      int c = c0 + s * 64;
      int row = c >> 2, kc = (c & 3) * 8;
      load_lds16(A + (size_t)(bm * 128 + row) * K + k0 + kc, As + c * 8);
      load_lds16(Bt + (size_t)(bn * 128 + row) * K + k0 + kc, Bs + c * 8);
    }
    __syncthreads();
    s16x8 af[4], bfr[4];
#pragma unroll
    for (int i = 0; i < 4; ++i) {
      af[i]  = *(const s16x8*)(As + (wm * 64 + i * 16 + l15) * 32 + quad * 8);
      bfr[i] = *(const s16x8*)(Bs + (wn * 64 + i * 16 + l15) * 32 + quad * 8);
    }
#pragma unroll
    for (int i = 0; i < 4; ++i)
#pragma unroll
      for (int j = 0; j < 4; ++j)
        acc[i][j] = __builtin_amdgcn_mfma_f32_16x16x32_bf16(af[i], bfr[j], acc[i][j], 0, 0, 0);
  }

  const int row0 = bm * 128 + wm * 64 + quad * 4;
  const int col0 = bn * 128 + wn * 64 + l15;
#pragma unroll
  for (int i = 0; i < 4; ++i)
#pragma unroll
    for (int j = 0; j < 4; ++j)
#pragma unroll
      for (int r = 0; r < 4; ++r) {
        size_t idx = (size_t)(row0 + i * 16 + r) * N + (col0 + j * 16);
        if constexpr (OUT_BF16) ((unsigned short*)Cout)[idx] = f2bf(acc[i][j][r]);
        else                    ((float*)Cout)[idx] = acc[i][j][r];
      }
}

// ---------------- flash attention v4 ----------------
// 256 threads / 4 waves; wave owns 32 q-rows (two 16-row tiles sharing K/V frags).
// Double-buffered K/V (one barrier per j-block, loads overlap compute).
// Grid 512 with CU-pairing: blocks p, p+256 share a CU -> q-tiles lq, 15-lq.
// LDS: Qs 16K (Q tile, later wave-private P strips) + K/V dbuf 32K = 48K.
__global__ __launch_bounds__(256) void attn_kernel(const unsigned short* __restrict__ qkv,
                                                   const unsigned short* __restrict__ Vt,
                                                   unsigned short* __restrict__ Y) {
  __shared__ unsigned short Qs[128 * 64];
  __shared__ unsigned short Ks[2][64 * 64];
  __shared__ unsigned short Vs[2][64 * 64];
  const int tid = threadIdx.x;
  const int wave = tid >> 6, lane = tid & 63;
  const int l15 = lane & 15, quad = lane >> 4;
  const int sx = l15 & 7;

  const int p = blockIdx.x;
  const int r_ = p >> 8, c_ = p & 255;
  const int m_ = c_ & 15, g_ = c_ >> 4;
  const int bh = g_ + 16 * r_;
  const int lq = r_ ? (15 - m_) : m_;
  const int q0 = lq * 128;
  const int b = bh >> 4, h = bh & 15;
  const size_t base = (size_t)b * 2048 * 3072 + h * 64;
  const size_t vbase = (size_t)bh * 64 * 2048;

  const int srow = tid >> 3, scc = tid & 7;       // staging coords (one chunk id = tid)
  const int skc = (scc ^ (srow & 7)) * 8;

  // stage Q tile 128x64 (swizzled): 1024 chunks, 4/thread
#pragma unroll
  for (int s = 0; s < 4; ++s) {
    int cid = tid + s * 256;
    int row = cid >> 3, cc = cid & 7;
    int kc = (cc ^ (row & 7)) * 8;
    load_lds16(qkv + base + (size_t)(q0 + row) * 3072 + kc, Qs + cid * 8);
  }
  // stage K/V for j0=0 into buf 0 (512 chunks each, 2/thread)
#pragma unroll
  for (int s = 0; s < 2; ++s) {
    int c = tid + s * 256;
    int row = c >> 3, cc = c & 7;
    int kc = (cc ^ (row & 7)) * 8;
    load_lds16(qkv + base + (size_t)row * 3072 + 1024 + kc, &Ks[0][0] + c * 8);
    load_lds16(Vt + vbase + (size_t)row * 2048 + kc, &Vs[0][0] + c * 8);
  }
  __syncthreads();

  const int qrow_w0 = q0 + wave * 32;            // wave's first q row
  s16x8 qf[2][2];
#pragma unroll
  for (int t = 0; t < 2; ++t) {
    const unsigned short* Qr = Qs + (wave * 32 + t * 16 + l15) * 64;
    qf[t][0] = *(const s16x8*)(Qr + ((quad    ) ^ sx) * 8);
    qf[t][1] = *(const s16x8*)(Qr + ((quad + 4) ^ sx) * 8);
  }
  unsigned short* Pw = Qs + wave * 32 * 64;      // wave-private P strips (2 x 16 rows)

  f32x4 o[2][4] = {};
  float m_i[2][4], l_i[2][4];
#pragma unroll
  for (int t = 0; t < 2; ++t)
#pragma unroll
    for (int r = 0; r < 4; ++r) { m_i[t][r] = -1e30f; l_i[t][r] = 0.f; }
  const float kScale = 0.125f * 1.44269504f;     // 1/sqrt(64) * log2(e)

  for (int j0 = 0; j0 <= q0 + 64; j0 += 64) {
    const int cur = (j0 >> 6) & 1;
    if (j0) __syncthreads();                     // drains staged buf[cur]; frees buf[1-cur]
    if (j0 <= q0) {                              // stage j0+64 into buf[1-cur]
      const int nxt = cur ^ 1;
#pragma unroll
      for (int s = 0; s < 2; ++s) {
        int c = tid + s * 256;
        int row = (c >> 3), cc = c & 7;
        int kc = (cc ^ (row & 7)) * 8;
        load_lds16(qkv + base + (size_t)(j0 + 64 + row) * 3072 + 1024 + kc, &Ks[nxt][0] + c * 8);
        load_lds16(Vt + vbase + (size_t)row * 2048 + j0 + 64 + kc, &Vs[nxt][0] + c * 8);
      }
    }

    if (j0 <= qrow_w0 + 31) {                    // wave active (both tiles active then)
      const unsigned short* Ksb = &Ks[cur][0];
      const unsigned short* Vsb = &Vs[cur][0];

      // K fragments, shared by both row-tiles
      s16x8 kf[4][2];
#pragma unroll
      for (int nt = 0; nt < 4; ++nt) {
        const unsigned short* Kr = Ksb + (nt * 16 + l15) * 64;
        kf[nt][0] = *(const s16x8*)(Kr + ((quad    ) ^ sx) * 8);
        kf[nt][1] = *(const s16x8*)(Kr + ((quad + 4) ^ sx) * 8);
      }

#pragma unroll
      for (int t = 0; t < 2; ++t) {
        const int qt0 = qrow_w0 + t * 16;
        f32x4 s[4];
#pragma unroll
        for (int nt = 0; nt < 4; ++nt) {
          f32x4 z = {};
          z = __builtin_amdgcn_mfma_f32_16x16x32_bf16(qf[t][0], kf[nt][0], z, 0, 0, 0);
          z = __builtin_amdgcn_mfma_f32_16x16x32_bf16(qf[t][1], kf[nt][1], z, 0, 0, 0);
          s[nt] = z;
        }

        if (j0 + 63 > qt0) {                     // tile crosses the diagonal
          const int qrow = qt0 + quad * 4;
#pragma unroll
          for (int nt = 0; nt < 4; ++nt) {
            int key = j0 + nt * 16 + l15;
#pragma unroll
            for (int r = 0; r < 4; ++r)
              if (key > qrow + r) s[nt][r] = -3e38f;
          }
        }

        // online softmax (raw-score domain, exp2)
        float tmax[4], alpha[4], rsum[4], mk[4];
#pragma unroll
        for (int r = 0; r < 4; ++r)
          tmax[r] = fmaxf(fmaxf(s[0][r], s[1][r]), fmaxf(s[2][r], s[3][r]));
#pragma unroll
        for (int off = 1; off < 16; off <<= 1)
#pragma unroll
          for (int r = 0; r < 4; ++r)
            tmax[r] = fmaxf(tmax[r], __shfl_xor(tmax[r], off, 64));
#pragma unroll
        for (int r = 0; r < 4; ++r) {
          float mn = fmaxf(m_i[t][r], tmax[r]);
          alpha[r] = __builtin_amdgcn_exp2f((m_i[t][r] - mn) * kScale);
          m_i[t][r] = mn;
          mk[r] = mn * kScale;
          rsum[r] = 0.f;
        }
#pragma unroll
        for (int nt = 0; nt < 4; ++nt)
#pragma unroll
          for (int r = 0; r < 4; ++r) {
            float pv = __builtin_amdgcn_exp2f(__builtin_fmaf(s[nt][r], kScale, -mk[r]));
            s[nt][r] = pv;
            rsum[r] += pv;
          }
#pragma unroll
        for (int off = 1; off < 16; off <<= 1)
#pragma unroll
          for (int r = 0; r < 4; ++r)
            rsum[r] += __shfl_xor(rsum[r], off, 64);
#pragma unroll
        for (int r = 0; r < 4; ++r)
          l_i[t][r] = l_i[t][r] * alpha[r] + rsum[r];
#pragma unroll
        for (int dt = 0; dt < 4; ++dt)
#pragma unroll
          for (int r = 0; r < 4; ++r)
            o[t][dt][r] *= alpha[r];

        // P tile -> wave-private LDS strip (no barrier: strip is wave-private)
        unsigned short* Pt = Pw + t * 16 * 64;
        const int l15h = l15 >> 3, l15l = l15 & 7;
#pragma unroll
        for (int nt = 0; nt < 4; ++nt)
#pragma unroll
          for (int r = 0; r < 4; ++r) {
            int prow = quad * 4 + r;
            Pt[prow * 64 + ((2 * nt + l15h) ^ (prow & 7)) * 8 + l15l] = f2bf_trunc(s[nt][r]);
          }
      }

      // V fragments, shared by both row-tiles
      s16x8 vf[4][2];
#pragma unroll
      for (int dt = 0; dt < 4; ++dt) {
        const unsigned short* Vr = Vsb + (dt * 16 + l15) * 64;
        vf[dt][0] = *(const s16x8*)(Vr + ((quad    ) ^ sx) * 8);
        vf[dt][1] = *(const s16x8*)(Vr + ((quad + 4) ^ sx) * 8);
      }

#pragma unroll
      for (int t = 0; t < 2; ++t) {
        const unsigned short* Pt = Pw + t * 16 * 64;
        s16x8 pf[2];
        pf[0] = *(const s16x8*)(Pt + l15 * 64 + ((quad    ) ^ sx) * 8);
        pf[1] = *(const s16x8*)(Pt + l15 * 64 + ((quad + 4) ^ sx) * 8);
#pragma unroll
        for (int dt = 0; dt < 4; ++dt) {
          o[t][dt] = __builtin_amdgcn_mfma_f32_16x16x32_bf16(pf[0], vf[dt][0], o[t][dt], 0, 0, 0);
          o[t][dt] = __builtin_amdgcn_mfma_f32_16x16x32_bf16(pf[1], vf[dt][1], o[t][dt], 0, 0, 0);
        }
      }
    }
  }

#pragma unroll
  for (int t = 0; t < 2; ++t) {
#pragma unroll
    for (int r = 0; r < 4; ++r)
      l_i[t][r] = 1.0f / l_i[t][r];
    const size_t yrow = (size_t)(b * 2048 + qrow_w0 + t * 16 + quad * 4);
#pragma unroll
    for (int dt = 0; dt < 4; ++dt)
#pragma unroll
      for (int r = 0; r < 4; ++r)
        Y[(yrow + r) * 1024 + h * 64 + dt * 16 + l15] = f2bf(o[t][dt][r] * l_i[t][r]);
  }
}

extern "C" void kernel_launch(void* const* d_in, const int* in_sizes, int n_in,
                              void* d_out, int out_size, void* d_ws, size_t ws_size,
                              hipStream_t stream) {
  const float* x      = (const float*)d_in[0];  // [2,2048,1024]
  const float* w_qkv  = (const float*)d_in[1];  // [1024,3072]
  const float* w_proj = (const float*)d_in[2];  // [1024,1024]
  char* ws = (char*)d_ws;
  unsigned short* xb     = (unsigned short*)(ws);                      //  8 MiB [4096,1024]
  unsigned short* wqkvT  = (unsigned short*)(ws + (size_t)(8  << 20)); //  6 MiB [3072,1024]
  unsigned short* wprojT = (unsigned short*)(ws + (size_t)(14 << 20)); //  2 MiB [1024,1024]
  unsigned short* qkv    = (unsigned short*)(ws + (size_t)(16 << 20)); // 24 MiB [4096,3072]
  unsigned short* y      = (unsigned short*)(ws + (size_t)(40 << 20)); //  8 MiB [4096,1024]
  unsigned short* Vt     = (unsigned short*)(ws + (size_t)(48 << 20)); //  8 MiB [32,64,2048]

  f32_to_bf16_kernel<<<4096, 256, 0, stream>>>(x, xb, 1048576);
  transpose_f32_bf16<<<dim3(96, 32), dim3(32, 8), 0, stream>>>(w_qkv, wqkvT, 1024, 3072);
  transpose_f32_bf16<<<dim3(32, 32), dim3(32, 8), 0, stream>>>(w_proj, wprojT, 1024, 1024);
  gemm_bt<true><<<dim3(24, 32), 256, 0, stream>>>(xb, wqkvT, qkv, 4096, 3072, 1024);
  transpose_v<<<dim3(32, 32), 256, 0, stream>>>(qkv, Vt);
  attn_kernel<<<512, 256, 0, stream>>>(qkv, Vt, y);
  gemm_bt<false><<<dim3(8, 32), 256, 0, stream>>>(y, wprojT, d_out, 4096, 1024, 1024);
}

// Round 5
// 225.110 us; speedup vs baseline: 1.0316x; 1.0316x over previous
//
#include <hip/hip_runtime.h>

#define AS1 __attribute__((address_space(1)))
#define AS3 __attribute__((address_space(3)))

using f32x4 = __attribute__((ext_vector_type(4))) float;
using s16x8 = __attribute__((ext_vector_type(8))) short;
using u16x4 = __attribute__((ext_vector_type(4))) unsigned short;

__device__ __forceinline__ unsigned short f2bf(float f) {
  union { float f; unsigned u; } v; v.f = f;
  unsigned u = v.u;
  return (unsigned short)((u + 0x7FFFu + ((u >> 16) & 1u)) >> 16);  // RNE
}

__device__ __forceinline__ unsigned short f2bf_trunc(float f) {
  union { float f; unsigned u; } v; v.f = f;
  return (unsigned short)(v.u >> 16);  // truncate: fine for P in [0,1]
}

__device__ __forceinline__ void load_lds16(const void* g, void* l) {
  __builtin_amdgcn_global_load_lds((const AS1 void*)g, (AS3 void*)l, 16, 0, 0);
}

// ---------------- fp32 -> bf16 cast (x) ----------------
__global__ __launch_bounds__(256) void f32_to_bf16_kernel(const float* __restrict__ in,
                                                          unsigned short* __restrict__ out,
                                                          int n4) {
  int i = blockIdx.x * 256 + threadIdx.x;
  if (i < n4) {
    float4 v = ((const float4*)in)[i];
    u16x4 o;
    o.x = f2bf(v.x); o.y = f2bf(v.y); o.z = f2bf(v.z); o.w = f2bf(v.w);
    ((u16x4*)out)[i] = o;
  }
}

// ---------------- fp32 [R][C] -> bf16 [C][R] transpose (weights) ----------------
__global__ __launch_bounds__(256) void transpose_f32_bf16(const float* __restrict__ in,
                                                          unsigned short* __restrict__ out,
                                                          int R, int C) {
  __shared__ float tile[32][33];
  int x = blockIdx.x * 32 + threadIdx.x;
  int y0 = blockIdx.y * 32;
  for (int j = threadIdx.y; j < 32; j += 8)
    tile[j][threadIdx.x] = in[(size_t)(y0 + j) * C + x];
  __syncthreads();
  int x2 = blockIdx.y * 32 + threadIdx.x;
  int y2 = blockIdx.x * 32;
  for (int j = threadIdx.y; j < 32; j += 8)
    out[(size_t)(y2 + j) * R + x2] = f2bf(tile[threadIdx.x][j]);
}

// ---------------- bf16 GEMM: C[M,N] = A[M,K] * Bt[N,K]^T (m97 structure) ----------------
// MODE 0: f32 output.  MODE 1: bf16 output.
// MODE 2: bf16 output; N==3072 QKV layout — V column-blocks (bn>=16) are written
//         TRANSPOSED into Vt[b][h][d][s] (b64 stores along s) and NOT into C.
template <int MODE>
__global__ __launch_bounds__(256) void gemm_bt(const unsigned short* __restrict__ A,
                                               const unsigned short* __restrict__ Bt,
                                               void* __restrict__ Cout,
                                               unsigned short* __restrict__ Vt,
                                               int M, int N, int K) {
  __shared__ unsigned short As[128 * 32];
  __shared__ unsigned short Bs[128 * 32];
  const int tid = threadIdx.x;
  const int wave = tid >> 6, lane = tid & 63;
  const int l15 = lane & 15, quad = lane >> 4;
  const int wm = wave & 1, wn = wave >> 1;
  const int bm = blockIdx.y, bn = blockIdx.x;

  f32x4 acc[4][4] = {};

  const int c0 = wave * 128 + lane;
  for (int k0 = 0; k0 < K; k0 += 32) {
    __syncthreads();
#pragma unroll
    for (int s = 0; s < 2; ++s) {
      int c = c0 + s * 64;
      int row = c >> 2, kc = (c & 3) * 8;
      load_lds16(A + (size_t)(bm * 128 + row) * K + k0 + kc, As + c * 8);
      load_lds16(Bt + (size_t)(bn * 128 + row) * K + k0 + kc, Bs + c * 8);
    }
    __syncthreads();
    s16x8 af[4], bfr[4];
#pragma unroll
    for (int i = 0; i < 4; ++i) {
      af[i]  = *(const s16x8*)(As + (wm * 64 + i * 16 + l15) * 32 + quad * 8);
      bfr[i] = *(const s16x8*)(Bs + (wn * 64 + i * 16 + l15) * 32 + quad * 8);
    }
#pragma unroll
    for (int i = 0; i < 4; ++i)
#pragma unroll
      for (int j = 0; j < 4; ++j)
        acc[i][j] = __builtin_amdgcn_mfma_f32_16x16x32_bf16(af[i], bfr[j], acc[i][j], 0, 0, 0);
  }

  const int row0 = bm * 128 + wm * 64 + quad * 4;
  const int col0 = bn * 128 + wn * 64 + l15;

  if (MODE == 2 && bn >= 16) {
    // V tile -> Vt[b][h][d][s], d = (col-2048)&63, h = (col-2048)>>6 (wave-uniform)
    const int b_ = row0 >> 11;                     // rows stay within one batch (2048%128==0)
    const int vcol0 = bn * 128 + wn * 64 - 2048;   // multiple of 64
    const int h_ = vcol0 >> 6;
    const size_t vtb = ((size_t)(b_ * 16 + h_)) * 64 * 2048;
    const int s_base = (row0 & 2047);
#pragma unroll
    for (int i = 0; i < 4; ++i)
#pragma unroll
      for (int j = 0; j < 4; ++j) {
        u16x4 pk;
#pragma unroll
        for (int r = 0; r < 4; ++r) pk[r] = f2bf(acc[i][j][r]);
        const int d = j * 16 + l15;
        *(u16x4*)(Vt + vtb + (size_t)d * 2048 + s_base + i * 16) = pk;
      }
    return;
  }

#pragma unroll
  for (int i = 0; i < 4; ++i)
#pragma unroll
    for (int j = 0; j < 4; ++j)
#pragma unroll
      for (int r = 0; r < 4; ++r) {
        size_t idx = (size_t)(row0 + i * 16 + r) * N + (col0 + j * 16);
        if (MODE == 0) ((float*)Cout)[idx] = acc[i][j][r];
        else           ((unsigned short*)Cout)[idx] = f2bf(acc[i][j][r]);
      }
}

// ---------------- flash attention (v3, verified 69.7 us) ----------------
// 128 q-rows/block, 8 waves (wave w owns rows [q0+16w, q0+16w+16)), grid 512.
// CU-balanced swizzle: blocks p and p+256 share a CU under round-robin dispatch;
// they get q-tiles lq and 15-lq -> constant work per CU.
// LDS tiles swizzled (chunk cc of row r at physical cc^(r&7)); Qs doubles as the
// wave-private P buffer after qf is lifted to registers.
__global__ __launch_bounds__(512) void attn_kernel(const unsigned short* __restrict__ qkv,
                                                   const unsigned short* __restrict__ Vt,
                                                   unsigned short* __restrict__ Y) {
  __shared__ unsigned short Qs[128 * 64];  // Q tile, then P buffer (wave-private strips)
  __shared__ unsigned short Ks[64 * 64];
  __shared__ unsigned short Vs[64 * 64];   // Vt tile: rows = d, cols = keys
  const int tid = threadIdx.x;
  const int wave = tid >> 6, lane = tid & 63;
  const int l15 = lane & 15, quad = lane >> 4;
  const int sx = l15 & 7;

  const int p = blockIdx.x;
  const int r_ = p >> 8, c_ = p & 255;
  const int m_ = c_ & 15, g_ = c_ >> 4;
  const int bh = g_ + 16 * r_;
  const int lq = r_ ? (15 - m_) : m_;
  const int q0 = lq * 128;
  const int b = bh >> 4, h = bh & 15;
  const size_t base = (size_t)b * 2048 * 3072 + h * 64;
  const size_t vbase = (size_t)bh * 64 * 2048;

  // stage Q tile 128x64 (swizzled): 1024 chunks, 2/thread
#pragma unroll
  for (int s = 0; s < 2; ++s) {
    int cid = tid + s * 512;
    int row = cid >> 3, cc = cid & 7;
    int kc = (cc ^ (row & 7)) * 8;
    load_lds16(qkv + base + (size_t)(q0 + row) * 3072 + kc, Qs + cid * 8);
  }
  __syncthreads();
  const int qr = wave * 16 + l15;
  s16x8 qf[2];
  qf[0] = *(const s16x8*)(Qs + qr * 64 + ((quad    ) ^ sx) * 8);
  qf[1] = *(const s16x8*)(Qs + qr * 64 + ((quad + 4) ^ sx) * 8);

  f32x4 o[4] = {};
  float m_i[4] = {-1e30f, -1e30f, -1e30f, -1e30f};
  float l_i[4] = {0.f, 0.f, 0.f, 0.f};
  const float kScale = 0.125f * 1.44269504f;  // 1/sqrt(64) * log2(e)
  const int qrow_w0 = q0 + wave * 16;         // wave's first q row
  unsigned short* Pw = Qs + wave * 16 * 64;   // wave-private P strip

  for (int j0 = 0; j0 <= q0 + 64; j0 += 64) {
    __syncthreads();
    {
      int row = tid >> 3, cc = tid & 7;
      int kc = (cc ^ (row & 7)) * 8;
      load_lds16(qkv + base + (size_t)(j0 + row) * 3072 + 1024 + kc, Ks + tid * 8);
      load_lds16(Vt + vbase + (size_t)row * 2048 + j0 + kc, Vs + tid * 8);
    }
    __syncthreads();

    if (j0 <= qrow_w0 + 15) {  // wave has at least one unmasked row in this j-block
      // S = Q K^T (raw scores; scale folded into exp2 arg later)
      f32x4 s[4];
#pragma unroll
      for (int nt = 0; nt < 4; ++nt) {
        const int kr = nt * 16 + l15;
        s16x8 kf0 = *(const s16x8*)(Ks + kr * 64 + ((quad    ) ^ sx) * 8);
        s16x8 kf1 = *(const s16x8*)(Ks + kr * 64 + ((quad + 4) ^ sx) * 8);
        f32x4 z = {};
        z = __builtin_amdgcn_mfma_f32_16x16x32_bf16(qf[0], kf0, z, 0, 0, 0);
        z = __builtin_amdgcn_mfma_f32_16x16x32_bf16(qf[1], kf1, z, 0, 0, 0);
        s[nt] = z;
      }

      // causal mask only where the j-block can cross the diagonal (wave-uniform)
      if (j0 + 63 > qrow_w0) {
        const int qrow = qrow_w0 + quad * 4;
#pragma unroll
        for (int nt = 0; nt < 4; ++nt) {
          int key = j0 + nt * 16 + l15;
#pragma unroll
          for (int r = 0; r < 4; ++r)
            if (key > qrow + r) s[nt][r] = -3e38f;
        }
      }

      // online softmax, raw-score domain; p = exp2(fma(s, kScale, -m*kScale))
      float tmax[4], alpha[4], rsum[4], mk[4];
#pragma unroll
      for (int r = 0; r < 4; ++r)
        tmax[r] = fmaxf(fmaxf(s[0][r], s[1][r]), fmaxf(s[2][r], s[3][r]));
#pragma unroll
      for (int off = 1; off < 16; off <<= 1)
#pragma unroll
        for (int r = 0; r < 4; ++r)
          tmax[r] = fmaxf(tmax[r], __shfl_xor(tmax[r], off, 64));
#pragma unroll
      for (int r = 0; r < 4; ++r) {
        float mn = fmaxf(m_i[r], tmax[r]);
        alpha[r] = __builtin_amdgcn_exp2f((m_i[r] - mn) * kScale);
        m_i[r] = mn;
        mk[r] = mn * kScale;
        rsum[r] = 0.f;
      }
#pragma unroll
      for (int nt = 0; nt < 4; ++nt)
#pragma unroll
        for (int r = 0; r < 4; ++r) {
          float pv = __builtin_amdgcn_exp2f(__builtin_fmaf(s[nt][r], kScale, -mk[r]));
          s[nt][r] = pv;
          rsum[r] += pv;
        }
#pragma unroll
      for (int off = 1; off < 16; off <<= 1)
#pragma unroll
        for (int r = 0; r < 4; ++r)
          rsum[r] += __shfl_xor(rsum[r], off, 64);
#pragma unroll
      for (int r = 0; r < 4; ++r)
        l_i[r] = l_i[r] * alpha[r] + rsum[r];
#pragma unroll
      for (int dt = 0; dt < 4; ++dt)
#pragma unroll
        for (int r = 0; r < 4; ++r)
          o[dt][r] *= alpha[r];

      // P: C-layout -> A-layout via wave-private LDS strip (no barrier needed)
      const int l15h = l15 >> 3, l15l = l15 & 7;
#pragma unroll
      for (int nt = 0; nt < 4; ++nt)
#pragma unroll
        for (int r = 0; r < 4; ++r) {
          int prow = quad * 4 + r;
          Pw[prow * 64 + ((2 * nt + l15h) ^ (prow & 7)) * 8 + l15l] = f2bf_trunc(s[nt][r]);
        }

      s16x8 pf[2];
      pf[0] = *(const s16x8*)(Pw + l15 * 64 + ((quad    ) ^ sx) * 8);
      pf[1] = *(const s16x8*)(Pw + l15 * 64 + ((quad + 4) ^ sx) * 8);

      // O += P V
#pragma unroll
      for (int dt = 0; dt < 4; ++dt) {
        const int vr = dt * 16 + l15;
#pragma unroll
        for (int kk = 0; kk < 2; ++kk) {
          s16x8 vf = *(const s16x8*)(Vs + vr * 64 + ((quad + 4 * kk) ^ sx) * 8);
          o[dt] = __builtin_amdgcn_mfma_f32_16x16x32_bf16(pf[kk], vf, o[dt], 0, 0, 0);
        }
      }
    }
  }

#pragma unroll
  for (int r = 0; r < 4; ++r)
    l_i[r] = 1.0f / l_i[r];
  const size_t yrow = (size_t)(b * 2048 + qrow_w0 + quad * 4);
#pragma unroll
  for (int dt = 0; dt < 4; ++dt)
#pragma unroll
    for (int r = 0; r < 4; ++r)
      Y[(yrow + r) * 1024 + h * 64 + dt * 16 + l15] = f2bf(o[dt][r] * l_i[r]);
}

extern "C" void kernel_launch(void* const* d_in, const int* in_sizes, int n_in,
                              void* d_out, int out_size, void* d_ws, size_t ws_size,
                              hipStream_t stream) {
  const float* x      = (const float*)d_in[0];  // [2,2048,1024]
  const float* w_qkv  = (const float*)d_in[1];  // [1024,3072]
  const float* w_proj = (const float*)d_in[2];  // [1024,1024]
  char* ws = (char*)d_ws;
  unsigned short* xb     = (unsigned short*)(ws);                      //  8 MiB [4096,1024]
  unsigned short* wqkvT  = (unsigned short*)(ws + (size_t)(8  << 20)); //  6 MiB [3072,1024]
  unsigned short* wprojT = (unsigned short*)(ws + (size_t)(14 << 20)); //  2 MiB [1024,1024]
  unsigned short* qkv    = (unsigned short*)(ws + (size_t)(16 << 20)); // 24 MiB [4096,3072] (V region unused)
  unsigned short* y      = (unsigned short*)(ws + (size_t)(40 << 20)); //  8 MiB [4096,1024]
  unsigned short* Vt     = (unsigned short*)(ws + (size_t)(48 << 20)); //  8 MiB [32,64,2048]

  f32_to_bf16_kernel<<<4096, 256, 0, stream>>>(x, xb, 1048576);
  transpose_f32_bf16<<<dim3(96, 32), dim3(32, 8), 0, stream>>>(w_qkv, wqkvT, 1024, 3072);
  transpose_f32_bf16<<<dim3(32, 32), dim3(32, 8), 0, stream>>>(w_proj, wprojT, 1024, 1024);
  gemm_bt<2><<<dim3(24, 32), 256, 0, stream>>>(xb, wqkvT, qkv, Vt, 4096, 3072, 1024);
  attn_kernel<<<512, 512, 0, stream>>>(qkv, Vt, y);
  gemm_bt<0><<<dim3(8, 32), 256, 0, stream>>>(y, wprojT, d_out, nullptr, 4096, 1024, 1024);
}

// Round 7
// 208.597 us; speedup vs baseline: 1.1133x; 1.0792x over previous
//
#include <hip/hip_runtime.h>

#define AS1 __attribute__((address_space(1)))
#define AS3 __attribute__((address_space(3)))

using f32x4 = __attribute__((ext_vector_type(4))) float;
using s16x8 = __attribute__((ext_vector_type(8))) short;
using u16x4 = __attribute__((ext_vector_type(4))) unsigned short;

__device__ __forceinline__ unsigned short f2bf(float f) {
  union { float f; unsigned u; } v; v.f = f;
  unsigned u = v.u;
  return (unsigned short)((u + 0x7FFFu + ((u >> 16) & 1u)) >> 16);  // RNE
}

__device__ __forceinline__ unsigned short f2bf_trunc(float f) {
  union { float f; unsigned u; } v; v.f = f;
  return (unsigned short)(v.u >> 16);  // truncate: fine for P in [0,1]
}

__device__ __forceinline__ void load_lds16(const void* g, void* l) {
  __builtin_amdgcn_global_load_lds((const AS1 void*)g, (AS3 void*)l, 16, 0, 0);
}

// ---------------- fused prep: cast x + transpose both weights ----------------
// grid 8192x256: [0,4096) cast x; [4096,7168) w_qkv^T; [7168,8192) w_proj^T
__global__ __launch_bounds__(256) void prep_kernel(const float* __restrict__ x,
                                                   const float* __restrict__ w_qkv,
                                                   const float* __restrict__ w_proj,
                                                   unsigned short* __restrict__ xb,
                                                   unsigned short* __restrict__ wqkvT,
                                                   unsigned short* __restrict__ wprojT) {
  __shared__ float tile[32][33];
  const int bid = blockIdx.x, tid = threadIdx.x;
  if (bid < 4096) {
    int i = bid * 256 + tid;
    float4 v = ((const float4*)x)[i];
    u16x4 o;
    o.x = f2bf(v.x); o.y = f2bf(v.y); o.z = f2bf(v.z); o.w = f2bf(v.w);
    ((u16x4*)xb)[i] = o;
    return;
  }
  const float* in;
  unsigned short* out;
  int bx, by, R, C;
  if (bid < 7168) {
    int t = bid - 4096;
    bx = t % 96; by = t / 96; R = 1024; C = 3072;
    in = w_qkv; out = wqkvT;
  } else {
    int t = bid - 7168;
    bx = t % 32; by = t / 32; R = 1024; C = 1024;
    in = w_proj; out = wprojT;
  }
  const int tx = tid & 31, ty = tid >> 5;
  int xcol = bx * 32 + tx;
  int y0 = by * 32;
  for (int j = ty; j < 32; j += 8)
    tile[j][tx] = in[(size_t)(y0 + j) * C + xcol];
  __syncthreads();
  int x2 = by * 32 + tx;
  int y2 = bx * 32;
  for (int j = ty; j < 32; j += 8)
    out[(size_t)(y2 + j) * R + x2] = f2bf(tile[tx][j]);
}

// ---------------- V transpose: qkv V block [s][d] -> Vt[b][h][d][s] ----------------
__global__ __launch_bounds__(256) void transpose_v(const unsigned short* __restrict__ qkv,
                                                   unsigned short* __restrict__ Vt) {
  __shared__ unsigned short tile[64][65];
  const int tid = threadIdx.x;
  const int bh = blockIdx.y, b = bh >> 4, h = bh & 15;
  const int s0 = blockIdx.x * 64;
#pragma unroll
  for (int it = 0; it < 2; ++it) {
    int c = tid + it * 256;
    int row = c >> 3, cc = c & 7;
    s16x8 v = *(const s16x8*)(qkv + (size_t)(b * 2048 + s0 + row) * 3072 + 2048 + h * 64 + cc * 8);
#pragma unroll
    for (int j = 0; j < 8; ++j) tile[row][cc * 8 + j] = (unsigned short)v[j];
  }
  __syncthreads();
#pragma unroll
  for (int it = 0; it < 2; ++it) {
    int c = tid + it * 256;
    int d = c >> 3, sc = c & 7;
    s16x8 o;
#pragma unroll
    for (int j = 0; j < 8; ++j) o[j] = (short)tile[sc * 8 + j][d];
    *(s16x8*)(Vt + (size_t)bh * 64 * 2048 + (size_t)d * 2048 + s0 + sc * 8) = o;
  }
}

// ---------------- QKV GEMM: qkv[M,3072] = xb[M,K] * wqkvT[3072,K]^T, bf16 out ----------------
// m97 structure: 128x128 tile, BK=32, 4 waves.
__global__ __launch_bounds__(256) void gemm_qkv(const unsigned short* __restrict__ A,
                                                const unsigned short* __restrict__ Bt,
                                                unsigned short* __restrict__ C,
                                                int M, int N, int K) {
  __shared__ unsigned short As[128 * 32];
  __shared__ unsigned short Bs[128 * 32];
  const int tid = threadIdx.x;
  const int wave = tid >> 6, lane = tid & 63;
  const int l15 = lane & 15, quad = lane >> 4;
  const int wm = wave & 1, wn = wave >> 1;
  const int bm = blockIdx.y, bn = blockIdx.x;

  f32x4 acc[4][4] = {};

  const int c0 = wave * 128 + lane;
  for (int k0 = 0; k0 < K; k0 += 32) {
    __syncthreads();
#pragma unroll
    for (int s = 0; s < 2; ++s) {
      int c = c0 + s * 64;
      int row = c >> 2, kc = (c & 3) * 8;
      load_lds16(A + (size_t)(bm * 128 + row) * K + k0 + kc, As + c * 8);
      load_lds16(Bt + (size_t)(bn * 128 + row) * K + k0 + kc, Bs + c * 8);
    }
    __syncthreads();
    s16x8 af[4], bfr[4];
#pragma unroll
    for (int i = 0; i < 4; ++i) {
      af[i]  = *(const s16x8*)(As + (wm * 64 + i * 16 + l15) * 32 + quad * 8);
      bfr[i] = *(const s16x8*)(Bs + (wn * 64 + i * 16 + l15) * 32 + quad * 8);
    }
#pragma unroll
    for (int i = 0; i < 4; ++i)
#pragma unroll
      for (int j = 0; j < 4; ++j)
        acc[i][j] = __builtin_amdgcn_mfma_f32_16x16x32_bf16(af[i], bfr[j], acc[i][j], 0, 0, 0);
  }

  const int row0 = bm * 128 + wm * 64 + quad * 4;
  const int col0 = bn * 128 + wn * 64 + l15;
#pragma unroll
  for (int i = 0; i < 4; ++i)
#pragma unroll
    for (int j = 0; j < 4; ++j)
#pragma unroll
      for (int r = 0; r < 4; ++r)
        C[(size_t)(row0 + i * 16 + r) * N + (col0 + j * 16)] = f2bf(acc[i][j][r]);
}

// ---------------- proj GEMM: out[M,1024] = y[M,K] * wprojT[1024,K]^T, f32 out ----------------
// 128M x 64N tile -> 512 blocks (2/CU). 4 waves 2x2 over (128,64); per-wave 64x32.
__global__ __launch_bounds__(256) void gemm_proj(const unsigned short* __restrict__ A,
                                                 const unsigned short* __restrict__ Bt,
                                                 float* __restrict__ C,
                                                 int M, int N, int K) {
  __shared__ unsigned short As[128 * 32];
  __shared__ unsigned short Bs[64 * 32];
  const int tid = threadIdx.x;
  const int wave = tid >> 6, lane = tid & 63;
  const int l15 = lane & 15, quad = lane >> 4;
  const int wm = wave & 1, wn = wave >> 1;  // wn in 0..1
  const int bm = blockIdx.y, bn = blockIdx.x;

  f32x4 acc[4][2] = {};

  for (int k0 = 0; k0 < K; k0 += 32) {
    __syncthreads();
#pragma unroll
    for (int s = 0; s < 2; ++s) {
      int c = tid + s * 256;
      int row = c >> 2, kc = (c & 3) * 8;
      load_lds16(A + (size_t)(bm * 128 + row) * K + k0 + kc, As + c * 8);
    }
    {
      int c = tid;
      int row = c >> 2, kc = (c & 3) * 8;
      load_lds16(Bt + (size_t)(bn * 64 + row) * K + k0 + kc, Bs + c * 8);
    }
    __syncthreads();
    s16x8 af[4], bfr[2];
#pragma unroll
    for (int i = 0; i < 4; ++i)
      af[i] = *(const s16x8*)(As + (wm * 64 + i * 16 + l15) * 32 + quad * 8);
#pragma unroll
    for (int j = 0; j < 2; ++j)
      bfr[j] = *(const s16x8*)(Bs + (wn * 32 + j * 16 + l15) * 32 + quad * 8);
#pragma unroll
    for (int i = 0; i < 4; ++i)
#pragma unroll
      for (int j = 0; j < 2; ++j)
        acc[i][j] = __builtin_amdgcn_mfma_f32_16x16x32_bf16(af[i], bfr[j], acc[i][j], 0, 0, 0);
  }

  const int row0 = bm * 128 + wm * 64 + quad * 4;
  const int col0 = bn * 64 + wn * 32 + l15;
#pragma unroll
  for (int i = 0; i < 4; ++i)
#pragma unroll
    for (int j = 0; j < 2; ++j)
#pragma unroll
      for (int r = 0; r < 4; ++r)
        C[(size_t)(row0 + i * 16 + r) * N + (col0 + j * 16)] = acc[i][j][r];
}

// ---------------- flash attention (v3, verified 67 us) ----------------
__global__ __launch_bounds__(512) void attn_kernel(const unsigned short* __restrict__ qkv,
                                                   const unsigned short* __restrict__ Vt,
                                                   unsigned short* __restrict__ Y) {
  __shared__ unsigned short Qs[128 * 64];  // Q tile, then P buffer (wave-private strips)
  __shared__ unsigned short Ks[64 * 64];
  __shared__ unsigned short Vs[64 * 64];   // Vt tile: rows = d, cols = keys
  const int tid = threadIdx.x;
  const int wave = tid >> 6, lane = tid & 63;
  const int l15 = lane & 15, quad = lane >> 4;
  const int sx = l15 & 7;

  const int p = blockIdx.x;
  const int r_ = p >> 8, c_ = p & 255;
  const int m_ = c_ & 15, g_ = c_ >> 4;
  const int bh = g_ + 16 * r_;
  const int lq = r_ ? (15 - m_) : m_;
  const int q0 = lq * 128;
  const int b = bh >> 4, h = bh & 15;
  const size_t base = (size_t)b * 2048 * 3072 + h * 64;
  const size_t vbase = (size_t)bh * 64 * 2048;

#pragma unroll
  for (int s = 0; s < 2; ++s) {
    int cid = tid + s * 512;
    int row = cid >> 3, cc = cid & 7;
    int kc = (cc ^ (row & 7)) * 8;
    load_lds16(qkv + base + (size_t)(q0 + row) * 3072 + kc, Qs + cid * 8);
  }
  __syncthreads();
  const int qr = wave * 16 + l15;
  s16x8 qf[2];
  qf[0] = *(const s16x8*)(Qs + qr * 64 + ((quad    ) ^ sx) * 8);
  qf[1] = *(const s16x8*)(Qs + qr * 64 + ((quad + 4) ^ sx) * 8);

  f32x4 o[4] = {};
  float m_i[4] = {-1e30f, -1e30f, -1e30f, -1e30f};
  float l_i[4] = {0.f, 0.f, 0.f, 0.f};
  const float kScale = 0.125f * 1.44269504f;  // 1/sqrt(64) * log2(e)
  const int qrow_w0 = q0 + wave * 16;
  unsigned short* Pw = Qs + wave * 16 * 64;

  for (int j0 = 0; j0 <= q0 + 64; j0 += 64) {
    __syncthreads();
    {
      int row = tid >> 3, cc = tid & 7;
      int kc = (cc ^ (row & 7)) * 8;
      load_lds16(qkv + base + (size_t)(j0 + row) * 3072 + 1024 + kc, Ks + tid * 8);
      load_lds16(Vt + vbase + (size_t)row * 2048 + j0 + kc, Vs + tid * 8);
    }
    __syncthreads();

    if (j0 <= qrow_w0 + 15) {
      f32x4 s[4];
#pragma unroll
      for (int nt = 0; nt < 4; ++nt) {
        const int kr = nt * 16 + l15;
        s16x8 kf0 = *(const s16x8*)(Ks + kr * 64 + ((quad    ) ^ sx) * 8);
        s16x8 kf1 = *(const s16x8*)(Ks + kr * 64 + ((quad + 4) ^ sx) * 8);
        f32x4 z = {};
        z = __builtin_amdgcn_mfma_f32_16x16x32_bf16(qf[0], kf0, z, 0, 0, 0);
        z = __builtin_amdgcn_mfma_f32_16x16x32_bf16(qf[1], kf1, z, 0, 0, 0);
        s[nt] = z;
      }

      if (j0 + 63 > qrow_w0) {
        const int qrow = qrow_w0 + quad * 4;
#pragma unroll
        for (int nt = 0; nt < 4; ++nt) {
          int key = j0 + nt * 16 + l15;
#pragma unroll
          for (int r = 0; r < 4; ++r)
            if (key > qrow + r) s[nt][r] = -3e38f;
        }
      }

      float tmax[4], alpha[4], rsum[4], mk[4];
#pragma unroll
      for (int r = 0; r < 4; ++r)
        tmax[r] = fmaxf(fmaxf(s[0][r], s[1][r]), fmaxf(s[2][r], s[3][r]));
#pragma unroll
      for (int off = 1; off < 16; off <<= 1)
#pragma unroll
        for (int r = 0; r < 4; ++r)
          tmax[r] = fmaxf(tmax[r], __shfl_xor(tmax[r], off, 64));
#pragma unroll
      for (int r = 0; r < 4; ++r) {
        float mn = fmaxf(m_i[r], tmax[r]);
        alpha[r] = __builtin_amdgcn_exp2f((m_i[r] - mn) * kScale);
        m_i[r] = mn;
        mk[r] = mn * kScale;
        rsum[r] = 0.f;
      }
#pragma unroll
      for (int nt = 0; nt < 4; ++nt)
#pragma unroll
        for (int r = 0; r < 4; ++r) {
          float pv = __builtin_amdgcn_exp2f(__builtin_fmaf(s[nt][r], kScale, -mk[r]));
          s[nt][r] = pv;
          rsum[r] += pv;
        }
#pragma unroll
      for (int off = 1; off < 16; off <<= 1)
#pragma unroll
        for (int r = 0; r < 4; ++r)
          rsum[r] += __shfl_xor(rsum[r], off, 64);
#pragma unroll
      for (int r = 0; r < 4; ++r)
        l_i[r] = l_i[r] * alpha[r] + rsum[r];
#pragma unroll
      for (int dt = 0; dt < 4; ++dt)
#pragma unroll
        for (int r = 0; r < 4; ++r)
          o[dt][r] *= alpha[r];

      const int l15h = l15 >> 3, l15l = l15 & 7;
#pragma unroll
      for (int nt = 0; nt < 4; ++nt)
#pragma unroll
        for (int r = 0; r < 4; ++r) {
          int prow = quad * 4 + r;
          Pw[prow * 64 + ((2 * nt + l15h) ^ (prow & 7)) * 8 + l15l] = f2bf_trunc(s[nt][r]);
        }

      s16x8 pf[2];
      pf[0] = *(const s16x8*)(Pw + l15 * 64 + ((quad    ) ^ sx) * 8);
      pf[1] = *(const s16x8*)(Pw + l15 * 64 + ((quad + 4) ^ sx) * 8);

#pragma unroll
      for (int dt = 0; dt < 4; ++dt) {
        const int vr = dt * 16 + l15;
#pragma unroll
        for (int kk = 0; kk < 2; ++kk) {
          s16x8 vf = *(const s16x8*)(Vs + vr * 64 + ((quad + 4 * kk) ^ sx) * 8);
          o[dt] = __builtin_amdgcn_mfma_f32_16x16x32_bf16(pf[kk], vf, o[dt], 0, 0, 0);
        }
      }
    }
  }

#pragma unroll
  for (int r = 0; r < 4; ++r)
    l_i[r] = 1.0f / l_i[r];
  const size_t yrow = (size_t)(b * 2048 + qrow_w0 + quad * 4);
#pragma unroll
  for (int dt = 0; dt < 4; ++dt)
#pragma unroll
    for (int r = 0; r < 4; ++r)
      Y[(yrow + r) * 1024 + h * 64 + dt * 16 + l15] = f2bf(o[dt][r] * l_i[r]);
}

extern "C" void kernel_launch(void* const* d_in, const int* in_sizes, int n_in,
                              void* d_out, int out_size, void* d_ws, size_t ws_size,
                              hipStream_t stream) {
  const float* x      = (const float*)d_in[0];  // [2,2048,1024]
  const float* w_qkv  = (const float*)d_in[1];  // [1024,3072]
  const float* w_proj = (const float*)d_in[2];  // [1024,1024]
  char* ws = (char*)d_ws;
  unsigned short* xb     = (unsigned short*)(ws);                      //  8 MiB [4096,1024]
  unsigned short* wqkvT  = (unsigned short*)(ws + (size_t)(8  << 20)); //  6 MiB [3072,1024]
  unsigned short* wprojT = (unsigned short*)(ws + (size_t)(14 << 20)); //  2 MiB [1024,1024]
  unsigned short* qkv    = (unsigned short*)(ws + (size_t)(16 << 20)); // 24 MiB [4096,3072]
  unsigned short* y      = (unsigned short*)(ws + (size_t)(40 << 20)); //  8 MiB [4096,1024]
  unsigned short* Vt     = (unsigned short*)(ws + (size_t)(48 << 20)); //  8 MiB [32,64,2048]

  prep_kernel<<<8192, 256, 0, stream>>>(x, w_qkv, w_proj, xb, wqkvT, wprojT);
  gemm_qkv<<<dim3(24, 32), 256, 0, stream>>>(xb, wqkvT, qkv, 4096, 3072, 1024);
  transpose_v<<<dim3(32, 32), 256, 0, stream>>>(qkv, Vt);
  attn_kernel<<<512, 512, 0, stream>>>(qkv, Vt, y);
  gemm_proj<<<dim3(16, 32), 256, 0, stream>>>(y, wprojT, (float*)d_out, 4096, 1024, 1024);
}

// Round 8
// 182.946 us; speedup vs baseline: 1.2694x; 1.1402x over previous
//
#include <hip/hip_runtime.h>

#define AS1 __attribute__((address_space(1)))
#define AS3 __attribute__((address_space(3)))

using f32x4 = __attribute__((ext_vector_type(4))) float;
using s16x8 = __attribute__((ext_vector_type(8))) short;
using u16x4 = __attribute__((ext_vector_type(4))) unsigned short;
using u32x2 = __attribute__((ext_vector_type(2))) unsigned int;

__device__ __forceinline__ unsigned short f2bf(float f) {
  union { float f; unsigned u; } v; v.f = f;
  unsigned u = v.u;
  return (unsigned short)((u + 0x7FFFu + ((u >> 16) & 1u)) >> 16);  // RNE
}

__device__ __forceinline__ unsigned pack_bf2(float a, float b) {  // trunc; P in [0,1]
  union { float f; unsigned u; } x, y; x.f = a; y.f = b;
  return (x.u >> 16) | (y.u & 0xFFFF0000u);
}

__device__ __forceinline__ void load_lds16(const void* g, void* l) {
  __builtin_amdgcn_global_load_lds((const AS1 void*)g, (AS3 void*)l, 16, 0, 0);
}

// ---------------- fused prep: cast x + transpose both weights ----------------
__global__ __launch_bounds__(256) void prep_kernel(const float* __restrict__ x,
                                                   const float* __restrict__ w_qkv,
                                                   const float* __restrict__ w_proj,
                                                   unsigned short* __restrict__ xb,
                                                   unsigned short* __restrict__ wqkvT,
                                                   unsigned short* __restrict__ wprojT) {
  __shared__ float tile[32][33];
  const int bid = blockIdx.x, tid = threadIdx.x;
  if (bid < 4096) {
    int i = bid * 256 + tid;
    float4 v = ((const float4*)x)[i];
    u16x4 o;
    o.x = f2bf(v.x); o.y = f2bf(v.y); o.z = f2bf(v.z); o.w = f2bf(v.w);
    ((u16x4*)xb)[i] = o;
    return;
  }
  const float* in;
  unsigned short* out;
  int bx, by, R, C;
  if (bid < 7168) {
    int t = bid - 4096;
    bx = t % 96; by = t / 96; R = 1024; C = 3072;
    in = w_qkv; out = wqkvT;
  } else {
    int t = bid - 7168;
    bx = t % 32; by = t / 32; R = 1024; C = 1024;
    in = w_proj; out = wprojT;
  }
  const int tx = tid & 31, ty = tid >> 5;
  int xcol = bx * 32 + tx;
  int y0 = by * 32;
  for (int j = ty; j < 32; j += 8)
    tile[j][tx] = in[(size_t)(y0 + j) * C + xcol];
  __syncthreads();
  int x2 = by * 32 + tx;
  int y2 = bx * 32;
  for (int j = ty; j < 32; j += 8)
    out[(size_t)(y2 + j) * R + x2] = f2bf(tile[tx][j]);
}

// ---------------- V transpose: qkv V block [s][d] -> Vt[b][h][d][s] ----------------
__global__ __launch_bounds__(256) void transpose_v(const unsigned short* __restrict__ qkv,
                                                   unsigned short* __restrict__ Vt) {
  __shared__ unsigned short tile[64][65];
  const int tid = threadIdx.x;
  const int bh = blockIdx.y, b = bh >> 4, h = bh & 15;
  const int s0 = blockIdx.x * 64;
#pragma unroll
  for (int it = 0; it < 2; ++it) {
    int c = tid + it * 256;
    int row = c >> 3, cc = c & 7;
    s16x8 v = *(const s16x8*)(qkv + (size_t)(b * 2048 + s0 + row) * 3072 + 2048 + h * 64 + cc * 8);
#pragma unroll
    for (int j = 0; j < 8; ++j) tile[row][cc * 8 + j] = (unsigned short)v[j];
  }
  __syncthreads();
#pragma unroll
  for (int it = 0; it < 2; ++it) {
    int c = tid + it * 256;
    int d = c >> 3, sc = c & 7;
    s16x8 o;
#pragma unroll
    for (int j = 0; j < 8; ++j) o[j] = (short)tile[sc * 8 + j][d];
    *(s16x8*)(Vt + (size_t)bh * 64 * 2048 + (size_t)d * 2048 + s0 + sc * 8) = o;
  }
}

// ---------------- QKV GEMM: BK=64, XOR-swizzled LDS (conflict-free frag reads) ----------------
// 128x128 tile, 16 K-iters. Rows are 64 ushorts = 128 B; chunk cc of row r stored
// at cc^(r&7) -> fragment b128 reads spread over all 32 banks.
__global__ __launch_bounds__(256) void gemm_qkv(const unsigned short* __restrict__ A,
                                                const unsigned short* __restrict__ Bt,
                                                unsigned short* __restrict__ C,
                                                int M, int N, int K) {
  __shared__ unsigned short As[128 * 64];
  __shared__ unsigned short Bs[128 * 64];
  const int tid = threadIdx.x;
  const int wave = tid >> 6, lane = tid & 63;
  const int l15 = lane & 15, quad = lane >> 4;
  const int sx = l15 & 7;
  const int wm = wave & 1, wn = wave >> 1;
  const int bm = blockIdx.y, bn = blockIdx.x;

  f32x4 acc[4][4] = {};

  for (int k0 = 0; k0 < K; k0 += 64) {
    __syncthreads();
#pragma unroll
    for (int s = 0; s < 4; ++s) {
      int c = tid + s * 256;
      int row = c >> 3, cc = c & 7;
      int kc = (cc ^ (row & 7)) * 8;
      load_lds16(A + (size_t)(bm * 128 + row) * K + k0 + kc, As + c * 8);
      load_lds16(Bt + (size_t)(bn * 128 + row) * K + k0 + kc, Bs + c * 8);
    }
    __syncthreads();
#pragma unroll
    for (int kk = 0; kk < 2; ++kk) {
      s16x8 af[4], bfr[4];
#pragma unroll
      for (int i = 0; i < 4; ++i) {
        af[i]  = *(const s16x8*)(As + (wm * 64 + i * 16 + l15) * 64 + ((quad + 4 * kk) ^ sx) * 8);
        bfr[i] = *(const s16x8*)(Bs + (wn * 64 + i * 16 + l15) * 64 + ((quad + 4 * kk) ^ sx) * 8);
      }
#pragma unroll
      for (int i = 0; i < 4; ++i)
#pragma unroll
        for (int j = 0; j < 4; ++j)
          acc[i][j] = __builtin_amdgcn_mfma_f32_16x16x32_bf16(af[i], bfr[j], acc[i][j], 0, 0, 0);
    }
  }

  const int row0 = bm * 128 + wm * 64 + quad * 4;
  const int col0 = bn * 128 + wn * 64 + l15;
#pragma unroll
  for (int i = 0; i < 4; ++i)
#pragma unroll
    for (int j = 0; j < 4; ++j)
#pragma unroll
      for (int r = 0; r < 4; ++r)
        C[(size_t)(row0 + i * 16 + r) * N + (col0 + j * 16)] = f2bf(acc[i][j][r]);
}

// ---------------- proj GEMM: 128Mx64N, BK=64, swizzled; f32 out ----------------
__global__ __launch_bounds__(256) void gemm_proj(const unsigned short* __restrict__ A,
                                                 const unsigned short* __restrict__ Bt,
                                                 float* __restrict__ C,
                                                 int M, int N, int K) {
  __shared__ unsigned short As[128 * 64];
  __shared__ unsigned short Bs[64 * 64];
  const int tid = threadIdx.x;
  const int wave = tid >> 6, lane = tid & 63;
  const int l15 = lane & 15, quad = lane >> 4;
  const int sx = l15 & 7;
  const int wm = wave & 1, wn = wave >> 1;  // wn in 0..1
  const int bm = blockIdx.y, bn = blockIdx.x;

  f32x4 acc[4][2] = {};

  for (int k0 = 0; k0 < K; k0 += 64) {
    __syncthreads();
#pragma unroll
    for (int s = 0; s < 4; ++s) {
      int c = tid + s * 256;
      int row = c >> 3, cc = c & 7;
      int kc = (cc ^ (row & 7)) * 8;
      load_lds16(A + (size_t)(bm * 128 + row) * K + k0 + kc, As + c * 8);
    }
#pragma unroll
    for (int s = 0; s < 2; ++s) {
      int c = tid + s * 256;
      int row = c >> 3, cc = c & 7;
      int kc = (cc ^ (row & 7)) * 8;
      load_lds16(Bt + (size_t)(bn * 64 + row) * K + k0 + kc, Bs + c * 8);
    }
    __syncthreads();
#pragma unroll
    for (int kk = 0; kk < 2; ++kk) {
      s16x8 af[4], bfr[2];
#pragma unroll
      for (int i = 0; i < 4; ++i)
        af[i] = *(const s16x8*)(As + (wm * 64 + i * 16 + l15) * 64 + ((quad + 4 * kk) ^ sx) * 8);
#pragma unroll
      for (int j = 0; j < 2; ++j)
        bfr[j] = *(const s16x8*)(Bs + (wn * 32 + j * 16 + l15) * 64 + ((quad + 4 * kk) ^ sx) * 8);
#pragma unroll
      for (int i = 0; i < 4; ++i)
#pragma unroll
        for (int j = 0; j < 2; ++j)
          acc[i][j] = __builtin_amdgcn_mfma_f32_16x16x32_bf16(af[i], bfr[j], acc[i][j], 0, 0, 0);
    }
  }

  const int row0 = bm * 128 + wm * 64 + quad * 4;
  const int col0 = bn * 64 + wn * 32 + l15;
#pragma unroll
  for (int i = 0; i < 4; ++i)
#pragma unroll
    for (int j = 0; j < 2; ++j)
#pragma unroll
      for (int r = 0; r < 4; ++r)
        C[(size_t)(row0 + i * 16 + r) * N + (col0 + j * 16)] = acc[i][j][r];
}

// ---------------- flash attention v5: S^T formulation ----------------
// S^T = K·Q^T (A=K-frag, B=Q-frag — same LDS reads as before, operands swapped).
// Lane (quad,l15) holds S^T[key=nt*16+quad*4+r][qrow=l15]: ONE q-row per lane ->
// softmax reduce = in-register over 16 + 2 shfl (vs 32 shfl); P written as 4
// ds_write_b64 (row-contiguous cols) and re-read as b128 B-frags for
// O^T = V^T·P^T (vf unchanged). o[dt][r] <-> d=dt*16+quad*4+r, qrow=l15.
__global__ __launch_bounds__(512) void attn_kernel(const unsigned short* __restrict__ qkv,
                                                   const unsigned short* __restrict__ Vt,
                                                   unsigned short* __restrict__ Y) {
  __shared__ unsigned short Qs[128 * 64];  // Q tile, then wave-private P strips
  __shared__ unsigned short Ks[64 * 64];
  __shared__ unsigned short Vs[64 * 64];   // Vt tile: rows = d, cols = keys
  const int tid = threadIdx.x;
  const int wave = tid >> 6, lane = tid & 63;
  const int l15 = lane & 15, quad = lane >> 4;
  const int sx = l15 & 7, sx2 = sx << 1;

  const int p = blockIdx.x;
  const int r_ = p >> 8, c_ = p & 255;
  const int m_ = c_ & 15, g_ = c_ >> 4;
  const int bh = g_ + 16 * r_;
  const int lq = r_ ? (15 - m_) : m_;
  const int q0 = lq * 128;
  const int b = bh >> 4, h = bh & 15;
  const size_t base = (size_t)b * 2048 * 3072 + h * 64;
  const size_t vbase = (size_t)bh * 64 * 2048;

#pragma unroll
  for (int s = 0; s < 2; ++s) {
    int cid = tid + s * 512;
    int row = cid >> 3, cc = cid & 7;
    int kc = (cc ^ (row & 7)) * 8;
    load_lds16(qkv + base + (size_t)(q0 + row) * 3072 + kc, Qs + cid * 8);
  }
  __syncthreads();
  s16x8 qf[2];
  qf[0] = *(const s16x8*)(Qs + (wave * 16 + l15) * 64 + ((quad    ) ^ sx) * 8);
  qf[1] = *(const s16x8*)(Qs + (wave * 16 + l15) * 64 + ((quad + 4) ^ sx) * 8);

  f32x4 o[4] = {};
  float m_i = -1e30f, l_i = 0.f;
  const float kScale = 0.125f * 1.44269504f;  // 1/sqrt(64) * log2(e)
  const int qrow_w0 = q0 + wave * 16;
  const int qrow = qrow_w0 + l15;             // this lane's q-row
  unsigned short* Pw = Qs + wave * 16 * 64;   // wave-private P strip [16 qrows][64 keys]

  for (int j0 = 0; j0 <= q0 + 64; j0 += 64) {
    __syncthreads();
    {
      int row = tid >> 3, cc = tid & 7;
      int kc = (cc ^ (row & 7)) * 8;
      load_lds16(qkv + base + (size_t)(j0 + row) * 3072 + 1024 + kc, Ks + tid * 8);
      load_lds16(Vt + vbase + (size_t)row * 2048 + j0 + kc, Vs + tid * 8);
    }
    __syncthreads();

    if (j0 <= qrow_w0 + 15) {
      // S^T tiles: A = K rows, B = Q^T (same fragment data, swapped operand slots)
      f32x4 s[4];
#pragma unroll
      for (int nt = 0; nt < 4; ++nt) {
        const int kr = nt * 16 + l15;
        s16x8 kf0 = *(const s16x8*)(Ks + kr * 64 + ((quad    ) ^ sx) * 8);
        s16x8 kf1 = *(const s16x8*)(Ks + kr * 64 + ((quad + 4) ^ sx) * 8);
        f32x4 z = {};
        z = __builtin_amdgcn_mfma_f32_16x16x32_bf16(kf0, qf[0], z, 0, 0, 0);
        z = __builtin_amdgcn_mfma_f32_16x16x32_bf16(kf1, qf[1], z, 0, 0, 0);
        s[nt] = z;
      }

      // causal mask: key = j0 + nt*16 + quad*4 + r vs this lane's qrow
      if (j0 + 63 > qrow_w0) {
#pragma unroll
        for (int nt = 0; nt < 4; ++nt) {
          int key0 = j0 + nt * 16 + quad * 4;
#pragma unroll
          for (int r = 0; r < 4; ++r)
            if (key0 + r > qrow) s[nt][r] = -3e38f;
        }
      }

      // online softmax: per-lane row; reduce over quads only (xor 16, 32)
      float tmax = s[0][0];
#pragma unroll
      for (int nt = 0; nt < 4; ++nt)
#pragma unroll
        for (int r = 0; r < 4; ++r)
          tmax = fmaxf(tmax, s[nt][r]);
      tmax = fmaxf(tmax, __shfl_xor(tmax, 16, 64));
      tmax = fmaxf(tmax, __shfl_xor(tmax, 32, 64));
      float mn = fmaxf(m_i, tmax);
      float alpha = __builtin_amdgcn_exp2f((m_i - mn) * kScale);
      m_i = mn;
      const float mk = mn * kScale;
      float rsum = 0.f;
#pragma unroll
      for (int nt = 0; nt < 4; ++nt)
#pragma unroll
        for (int r = 0; r < 4; ++r) {
          float pv = __builtin_amdgcn_exp2f(__builtin_fmaf(s[nt][r], kScale, -mk));
          s[nt][r] = pv;
          rsum += pv;
        }
      rsum += __shfl_xor(rsum, 16, 64);
      rsum += __shfl_xor(rsum, 32, 64);
      l_i = l_i * alpha + rsum;
#pragma unroll
      for (int dt = 0; dt < 4; ++dt)
#pragma unroll
        for (int r = 0; r < 4; ++r)
          o[dt][r] *= alpha;

      // P row l15, cols nt*16+quad*4..+3 -> one b64 per nt (8B-chunk XOR swizzle)
#pragma unroll
      for (int nt = 0; nt < 4; ++nt) {
        u32x2 pk;
        pk.x = pack_bf2(s[nt][0], s[nt][1]);
        pk.y = pack_bf2(s[nt][2], s[nt][3]);
        int phys = (nt * 4 + quad) ^ sx2;
        *(u32x2*)(Pw + l15 * 64 + phys * 4) = pk;
      }

      // B-frags: P^T[k=kk*32+quad*8+j][qrow=l15] = row l15, 8 contiguous cols
      s16x8 pf[2];
      pf[0] = *(const s16x8*)(Pw + l15 * 64 + (((quad * 2)    ) ^ sx2) * 4);
      pf[1] = *(const s16x8*)(Pw + l15 * 64 + (((quad * 2) + 8) ^ sx2) * 4);

      // O^T += V^T · P^T  (A = vf, unchanged reads)
#pragma unroll
      for (int dt = 0; dt < 4; ++dt) {
        const int vr = dt * 16 + l15;
        s16x8 vf0 = *(const s16x8*)(Vs + vr * 64 + ((quad    ) ^ sx) * 8);
        s16x8 vf1 = *(const s16x8*)(Vs + vr * 64 + ((quad + 4) ^ sx) * 8);
        o[dt] = __builtin_amdgcn_mfma_f32_16x16x32_bf16(vf0, pf[0], o[dt], 0, 0, 0);
        o[dt] = __builtin_amdgcn_mfma_f32_16x16x32_bf16(vf1, pf[1], o[dt], 0, 0, 0);
      }
    }
  }

  const float inv = 1.0f / l_i;
  const size_t yoff = (size_t)(b * 2048 + qrow) * 1024 + h * 64 + quad * 4;
#pragma unroll
  for (int dt = 0; dt < 4; ++dt) {
    u16x4 pk;
#pragma unroll
    for (int r = 0; r < 4; ++r) pk[r] = f2bf(o[dt][r] * inv);
    *(u16x4*)(Y + yoff + dt * 16) = pk;
  }
}

extern "C" void kernel_launch(void* const* d_in, const int* in_sizes, int n_in,
                              void* d_out, int out_size, void* d_ws, size_t ws_size,
                              hipStream_t stream) {
  const float* x      = (const float*)d_in[0];  // [2,2048,1024]
  const float* w_qkv  = (const float*)d_in[1];  // [1024,3072]
  const float* w_proj = (const float*)d_in[2];  // [1024,1024]
  char* ws = (char*)d_ws;
  unsigned short* xb     = (unsigned short*)(ws);                      //  8 MiB
  unsigned short* wqkvT  = (unsigned short*)(ws + (size_t)(8  << 20)); //  6 MiB
  unsigned short* wprojT = (unsigned short*)(ws + (size_t)(14 << 20)); //  2 MiB
  unsigned short* qkv    = (unsigned short*)(ws + (size_t)(16 << 20)); // 24 MiB
  unsigned short* y      = (unsigned short*)(ws + (size_t)(40 << 20)); //  8 MiB
  unsigned short* Vt     = (unsigned short*)(ws + (size_t)(48 << 20)); //  8 MiB

  prep_kernel<<<8192, 256, 0, stream>>>(x, w_qkv, w_proj, xb, wqkvT, wprojT);
  gemm_qkv<<<dim3(24, 32), 256, 0, stream>>>(xb, wqkvT, qkv, 4096, 3072, 1024);
  transpose_v<<<dim3(32, 32), 256, 0, stream>>>(qkv, Vt);
  attn_kernel<<<512, 512, 0, stream>>>(qkv, Vt, y);
  gemm_proj<<<dim3(16, 32), 256, 0, stream>>>(y, wprojT, (float*)d_out, 4096, 1024, 1024);
}